// Round 4
// baseline (123.144 us; speedup 1.0000x reference)
//
#include <hip/hip_runtime.h>

#define NROWS 262144
#define NE 5
#define TM 128                   // rows per block = 4 waves x 32
#define TILES (NROWS / TM)       // 2048

typedef __attribute__((ext_vector_type(8))) short short8;
typedef __attribute__((ext_vector_type(4))) float f32x4;
// 16B vector load with only 4B alignment guarantee: backend emits
// global_load_dwordx4 (gfx9+ unaligned-access-mode), no UB.
typedef __attribute__((ext_vector_type(4), aligned(4))) float f32x4u;

__device__ __forceinline__ unsigned short f2bf(float x) {
  unsigned u = __float_as_uint(x);
  u += 0x7FFF + ((u >> 16) & 1);   // round-to-nearest-even
  return (unsigned short)(u >> 16);
}

// ---------------- kernel 1: convert W1,W2 to transposed bf16 -----------------
// Wt[e][j][k] = W[e][k][j]  (MFMA B-fragments become contiguous 16B reads)
__global__ __launch_bounds__(256) void convw(const float* __restrict__ W1,
                                             const float* __restrict__ W2,
                                             unsigned short* __restrict__ Wt1,
                                             unsigned short* __restrict__ Wt2) {
  int idx = blockIdx.x * 256 + threadIdx.x;       // 0 .. 163839
  int which = idx / 81920;
  int rem = idx % 81920;
  int e = rem / 16384;
  int jk = rem % 16384;
  int j = jk / 128;
  int k = jk % 128;
  const float* W = which ? W2 : W1;
  unsigned short* Wt = which ? Wt2 : Wt1;
  Wt[e * 16384 + j * 128 + k] = f2bf(W[e * 16384 + k * 128 + j]);
}

// -------- kernel 2: classify rows into expert buckets (+ compact t) ---------
__global__ __launch_bounds__(256) void classify(const float* __restrict__ x,
                                                int* __restrict__ bucket,
                                                float* __restrict__ tc,
                                                int* __restrict__ cnt) {
  int r = blockIdx.x * 256 + threadIdx.x;
  float t = x[(size_t)r * 129];
  int e = (t >= 0.2f) + (t >= 0.4f) + (t >= 0.6f) + (t >= 0.8f);
  __shared__ int lc[NE];
  __shared__ int lb[NE];
  if (threadIdx.x < NE) lc[threadIdx.x] = 0;
  __syncthreads();
  int lpos = atomicAdd(&lc[e], 1);
  __syncthreads();
  if (threadIdx.x < NE) lb[threadIdx.x] = atomicAdd(&cnt[threadIdx.x], lc[threadIdx.x]);
  __syncthreads();
  size_t dst = (size_t)e * NROWS + lb[e] + lpos;
  bucket[dst] = r;
  tc[dst] = t;
}

// ---- kernel 3: per-expert MLP, 32 rows/wave, wide-load staging, no barriers -
__global__ __launch_bounds__(256, 4) void mlp(
    const float* __restrict__ x,
    const unsigned short* __restrict__ Wt1, const float* __restrict__ tw1, const float* __restrict__ b1,
    const unsigned short* __restrict__ Wt2, const float* __restrict__ tw2, const float* __restrict__ b2,
    const float* __restrict__ W3, const float* __restrict__ tw3, const float* __restrict__ b3,
    const int* __restrict__ bucket, const float* __restrict__ tc, const int* __restrict__ cnt,
    float* __restrict__ out) {
  int e = blockIdx.x / TILES;
  int it = blockIdx.x % TILES;
  int n = cnt[e];
  int i0 = it * TM;
  if (i0 >= n) return;

  __shared__ unsigned short hbuf[4][32 * 128];   // 8 KB per wave, swizzled

  int tid  = threadIdx.x;
  int wave = tid >> 6;
  int lane = tid & 63;
  int lr = lane & 15;        // A-row within 16-group / D-col within ct
  int lq = lane >> 4;        // k-quad / D-row-quad
  int sub = lane >> 5;       // which of the 2 rows this lane stages per instr
  int cb  = lane & 31;       // 16B block within a row (f32)
  int rbase = i0 + wave * 32;

  const int* bk = bucket + (size_t)e * NROWS;
  const float* tce = tc + (size_t)e * NROWS;

  // 32 bucketed row ids + t values for this wave, coalesced (dup on lanes>=32)
  int clampIdx = min(rbase + (lane & 31), n - 1);
  int rI = bk[clampIdx];
  float tv = tce[clampIdx];

  char* hp = (char*)hbuf[wave];

  // ---- stage f tile: 16 wide loads, instr i covers rows 2i,2i+1 (512B each) -
  f32x4u stg[16];
#pragma unroll
  for (int i = 0; i < 16; ++i) {
    int rid = __shfl(rI, 2 * i + sub);
    stg[i] = *(const f32x4u*)(x + (size_t)rid * 129 + 1 + cb * 4);
  }
#pragma unroll
  for (int i = 0; i < 16; ++i) {
    int rr = 2 * i + sub;
    unsigned long long p =
        (unsigned long long)f2bf(stg[i][0]) |
        ((unsigned long long)f2bf(stg[i][1]) << 16) |
        ((unsigned long long)f2bf(stg[i][2]) << 32) |
        ((unsigned long long)f2bf(stg[i][3]) << 48);
    int off = (rr * 256 + cb * 8) ^ ((rr & 7) << 4);
    *(unsigned long long*)(hp + off) = p;
  }

  // t values and output row ids for the D-rows this lane owns, via shuffle
  float t0[4], t1[4];
  int ro0[4], ro1[4];
#pragma unroll
  for (int rr = 0; rr < 4; ++rr) {
    t0[rr] = __shfl(tv, lq * 4 + rr);
    t1[rr] = __shfl(tv, 16 + lq * 4 + rr);
    ro0[rr] = __shfl(rI, lq * 4 + rr);
    ro1[rr] = __shfl(rI, 16 + lq * 4 + rr);
  }

  // wave-local LDS fence (rule 18)
  asm volatile("s_waitcnt lgkmcnt(0)" ::: "memory");
  __builtin_amdgcn_sched_barrier(0);

  short8 a0[4], a1[4];
#pragma unroll
  for (int ks = 0; ks < 4; ++ks) {
    int off0 = (lr * 256 + ks * 64 + lq * 16) ^ ((lr & 7) << 4);
    int off1 = ((16 + lr) * 256 + ks * 64 + lq * 16) ^ ((lr & 7) << 4);
    a0[ks] = *(const short8*)(hp + off0);
    a1[ks] = *(const short8*)(hp + off1);
  }

  const unsigned short* W1e = Wt1 + e * 16384;

  // ===== layer 1: h1 = relu(f @ W1 + t*tw1 + b1) -> same LDS (f is dead) ====
#pragma unroll
  for (int ct = 0; ct < 8; ++ct) {
    f32x4 acc0 = {0.f, 0.f, 0.f, 0.f};
    f32x4 acc1 = {0.f, 0.f, 0.f, 0.f};
#pragma unroll
    for (int ks = 0; ks < 4; ++ks) {
      short8 b = *(const short8*)(W1e + (ct * 16 + lr) * 128 + ks * 32 + lq * 8);
      acc0 = __builtin_amdgcn_mfma_f32_16x16x32_bf16(a0[ks], b, acc0, 0, 0, 0);
      acc1 = __builtin_amdgcn_mfma_f32_16x16x32_bf16(a1[ks], b, acc1, 0, 0, 0);
    }
    int col = ct * 16 + lr;
    float twv = tw1[e * 128 + col];
    float bv  = b1[e * 128 + col];
#pragma unroll
    for (int rr = 0; rr < 4; ++rr) {
      int row0 = lq * 4 + rr;
      int row1 = row0 + 16;
      float v0 = fmaxf(acc0[rr] + t0[rr] * twv + bv, 0.f);
      float v1 = fmaxf(acc1[rr] + t1[rr] * twv + bv, 0.f);
      *(unsigned short*)(hp + ((row0 * 256 + col * 2) ^ ((row0 & 7) << 4))) = f2bf(v0);
      *(unsigned short*)(hp + ((row1 * 256 + col * 2) ^ ((row1 & 7) << 4))) = f2bf(v1);
    }
  }

  asm volatile("s_waitcnt lgkmcnt(0)" ::: "memory");
  __builtin_amdgcn_sched_barrier(0);

#pragma unroll
  for (int ks = 0; ks < 4; ++ks) {
    int off0 = (lr * 256 + ks * 64 + lq * 16) ^ ((lr & 7) << 4);
    int off1 = ((16 + lr) * 256 + ks * 64 + lq * 16) ^ ((lr & 7) << 4);
    a0[ks] = *(const short8*)(hp + off0);
    a1[ks] = *(const short8*)(hp + off1);
  }

  // ===== layer 2 + fused layer 3: o += relu(h1@W2 + t*tw2 + b2) * W3 ========
  const unsigned short* W2e = Wt2 + e * 16384;
  const float* W3e = W3 + e * 128;
  float o0[4] = {0.f, 0.f, 0.f, 0.f};
  float o1[4] = {0.f, 0.f, 0.f, 0.f};
#pragma unroll
  for (int ct = 0; ct < 8; ++ct) {
    f32x4 acc0 = {0.f, 0.f, 0.f, 0.f};
    f32x4 acc1 = {0.f, 0.f, 0.f, 0.f};
#pragma unroll
    for (int ks = 0; ks < 4; ++ks) {
      short8 b = *(const short8*)(W2e + (ct * 16 + lr) * 128 + ks * 32 + lq * 8);
      acc0 = __builtin_amdgcn_mfma_f32_16x16x32_bf16(a0[ks], b, acc0, 0, 0, 0);
      acc1 = __builtin_amdgcn_mfma_f32_16x16x32_bf16(a1[ks], b, acc1, 0, 0, 0);
    }
    int col = ct * 16 + lr;
    float twv = tw2[e * 128 + col];
    float bv  = b2[e * 128 + col];
    float w3v = W3e[col];
#pragma unroll
    for (int rr = 0; rr < 4; ++rr) {
      float v0 = fmaxf(acc0[rr] + t0[rr] * twv + bv, 0.f);
      float v1 = fmaxf(acc1[rr] + t1[rr] * twv + bv, 0.f);
      o0[rr] += v0 * w3v;
      o1[rr] += v1 * w3v;
    }
  }

  // reduce over the 16 cols held across lanes lr=0..15 (xor stays in-group)
#pragma unroll
  for (int rr = 0; rr < 4; ++rr) {
    float s0 = o0[rr], s1 = o1[rr];
    s0 += __shfl_xor(s0, 1);  s1 += __shfl_xor(s1, 1);
    s0 += __shfl_xor(s0, 2);  s1 += __shfl_xor(s1, 2);
    s0 += __shfl_xor(s0, 4);  s1 += __shfl_xor(s1, 4);
    s0 += __shfl_xor(s0, 8);  s1 += __shfl_xor(s1, 8);
    o0[rr] = s0;  o1[rr] = s1;
  }

  if (lr == 0) {
    float tw3v = tw3[e];
    float b3v  = b3[e];
#pragma unroll
    for (int rr = 0; rr < 4; ++rr) {
      if (rbase + lq * 4 + rr < n)
        out[ro0[rr]] = o0[rr] + t0[rr] * tw3v + b3v;
      if (rbase + 16 + lq * 4 + rr < n)
        out[ro1[rr]] = o1[rr] + t1[rr] * tw3v + b3v;
    }
  }
}

extern "C" void kernel_launch(void* const* d_in, const int* in_sizes, int n_in,
                              void* d_out, int out_size, void* d_ws, size_t ws_size,
                              hipStream_t stream) {
  const float* x   = (const float*)d_in[0];
  const float* W1  = (const float*)d_in[1];
  const float* tw1 = (const float*)d_in[2];
  const float* b1  = (const float*)d_in[3];
  const float* W2  = (const float*)d_in[4];
  const float* tw2 = (const float*)d_in[5];
  const float* b2  = (const float*)d_in[6];
  const float* W3  = (const float*)d_in[7];
  const float* tw3 = (const float*)d_in[8];
  const float* b3  = (const float*)d_in[9];
  float* out = (float*)d_out;

  char* ws = (char*)d_ws;
  int* cnt = (int*)ws;                                   // 5 ints (256B reserved)
  int* bucket = (int*)(ws + 256);                        // 5*NROWS ints = 5 MB
  float* tcmp = (float*)(ws + 256 + (size_t)NE * NROWS * 4);        // 5 MB
  unsigned short* Wt1 = (unsigned short*)(ws + 256 + (size_t)NE * NROWS * 8);
  unsigned short* Wt2 = Wt1 + NE * 16384;

  hipMemsetAsync(cnt, 0, NE * sizeof(int), stream);
  convw<<<640, 256, 0, stream>>>(W1, W2, Wt1, Wt2);
  classify<<<NROWS / 256, 256, 0, stream>>>(x, bucket, tcmp, cnt);
  mlp<<<NE * TILES, 256, 0, stream>>>(x, Wt1, tw1, b1, Wt2, tw2, b2, W3, tw3, b3,
                                      bucket, tcmp, cnt, out);
}